// Round 9
// baseline (46.024 us; speedup 1.0000x reference)
//
#include <hip/hip_runtime.h>
#include <math.h>

#define SCALE 8
#define PSZ 32

// ---- constant twiddles: W_32^k = cos(2pi k/32) - i sin(2pi k/32), k=0..15 ----
__device__ constexpr float C32[16] = {
     1.000000000000000f,  0.980785280403230f,  0.923879532511287f,  0.831469612302545f,
     0.707106781186548f,  0.555570233019602f,  0.382683432365090f,  0.195090322016128f,
     0.000000000000000f, -0.195090322016128f, -0.382683432365090f, -0.555570233019602f,
    -0.707106781186548f, -0.831469612302545f, -0.923879532511287f, -0.980785280403230f };
__device__ constexpr float S32[16] = {
     0.000000000000000f,  0.195090322016128f,  0.382683432365090f,  0.555570233019602f,
     0.707106781186548f,  0.831469612302545f,  0.923879532511287f,  0.980785280403230f,
     1.000000000000000f,  0.980785280403230f,  0.923879532511287f,  0.831469612302545f,
     0.707106781186548f,  0.555570233019602f,  0.382683432365090f,  0.195090322016128f };

__device__ __forceinline__ constexpr int brev4(int i) {
    return ((i & 1) << 3) | ((i & 2) << 1) | ((i & 4) >> 1) | ((i & 8) >> 3);
}

// in-place 16-point radix-2 DIT FFT, fully unrolled (compile-time indices).
// Twiddle W16^(j*(16/m)) == W32^(j*(32/m)) -> same C32/S32 tables.
// Peak live state: 32 floats + temps (fits the ~60-VGPR budget the
// allocator insists on; the old monolithic fft32 needed 64+ live and paid
// ~2.8x VALU inflation in AGPR shuttling — R7/R8 post-mortems).
__device__ __forceinline__ void fft16(float re[16], float im[16]) {
#pragma unroll
    for (int i = 0; i < 16; ++i) {
        const int j = brev4(i);
        if (j > i) {
            float t = re[i]; re[i] = re[j]; re[j] = t;
            t = im[i]; im[i] = im[j]; im[j] = t;
        }
    }
#pragma unroll
    for (int s = 1; s <= 4; ++s) {
        const int m = 1 << s;
        const int h = m >> 1;
        const int tstep = 32 >> s;
#pragma unroll
        for (int k = 0; k < 16; k += m) {
#pragma unroll
            for (int j = 0; j < h; ++j) {
                const float wr = C32[j * tstep];
                const float wi = -S32[j * tstep];
                const int a = k + j;
                const int b = k + j + h;
                const float tr = wr * re[b] - wi * im[b];
                const float ti = wr * im[b] + wi * re[b];
                re[b] = re[a] - tr; im[b] = im[a] - ti;
                re[a] = re[a] + tr; im[a] = im[a] + ti;
            }
        }
    }
}

// bf16x2 pack/unpack (round-half-up via +0x8000)
__device__ __forceinline__ unsigned pack_bf2(float hi, float lo) {
    const unsigned uh = __float_as_uint(hi) + 0x8000u;
    const unsigned ul = __float_as_uint(lo) + 0x8000u;
    return (uh & 0xFFFF0000u) | (ul >> 16);
}
__device__ __forceinline__ float bf_hi(unsigned u) { return __uint_as_float(u & 0xFFFF0000u); }
__device__ __forceinline__ float bf_lo(unsigned u) { return __uint_as_float(u << 16); }

// ---- gray precompute: g = w0*R + w1*G + w2*B, vectorized float4 ----
__global__ __launch_bounds__(256) void gray_kernel(
        const float* __restrict__ x, const float* __restrict__ w,
        float* __restrict__ g, int n4, long long HW) {
    const int i = blockIdx.x * 256 + threadIdx.x;
    if (i >= n4) return;
    const float w0 = w[0], w1 = w[1], w2 = w[2];
    const float4 a = reinterpret_cast<const float4*>(x)[i];
    const float4 b = reinterpret_cast<const float4*>(x + HW)[i];
    const float4 c = reinterpret_cast<const float4*>(x + 2 * HW)[i];
    float4 o;
    o.x = w0 * a.x + w1 * b.x + w2 * c.x;
    o.y = w0 * a.y + w1 * b.y + w2 * c.y;
    o.z = w0 * a.z + w1 * b.z + w2 * c.z;
    o.w = w0 * a.w + w1 * b.w + w2 * c.w;
    reinterpret_cast<float4*>(g)[i] = o;
}

// 128-thread block = 2 independent waves; each wave handles 4 patches in its
// own private LDS slab (wave-local lgkmcnt fence instead of s_barrier).
//
// DIF-SPLIT STRUCTURE (R9): FFT32 is computed as two sequential FFT16s:
//   even bins  X[2k]   = FFT16( x[i] + x[i+16] )
//   odd bins   X[2k+1] = FFT16( (x[i] - x[i+16]) * W32^i )
// Hermitian-mirror pairs (k, 32-k) have equal parity, and the mask weights
// are parity-separable, so each half-spectrum is fully consumed before the
// other is built. Pass 2 re-reads its inputs (row: L1-hot gray; col: LDS).
// Peak register liveness ~50 floats instead of 104 -> no AGPR shuttling.
template <bool GRAY_PRE>
__global__ __launch_bounds__(128) void hfdft_patch_kernel(
        const float* __restrict__ x, const float* __restrict__ w,
        float* __restrict__ out, int H, int W, int mat_h, int mat_w) {
    __shared__ unsigned cb[8 * 528];   // 2 waves * 4 patches * 528 u32

    const int tid = threadIdx.x;
    const int wid = tid >> 6;
    const int lane = tid & 63;
    const int P0 = blockIdx.x * 8 + wid * 4;
    const int total = mat_h * mat_w;
    const long long HW = (long long)H * W;
    unsigned* cbw = cb + wid * 4 * 528;   // this wave's private slab

    // ================= row stage =================
    {
        const int g = lane >> 5, r = lane & 31;
        int pA = P0 + 2 * g;
        if (pA > total - 1) pA = total - 1;
        int pB = pA + 1; if (pB > total - 1) pB = total - 1;
        const int phA = pA / mat_w, pwA = pA % mat_w;
        const int phB = pB / mat_w, pwB = pB % mat_w;
        const bool adj = (phA == phB) && (pwB == pwA + 1);
        const int baseA = (phA * SCALE + r) * W + pwA * SCALE;
        const int baseB = (phB * SCALE + r) * W + pwB * SCALE;
        const float w0 = GRAY_PRE ? 0.0f : w[0];
        const float w1 = GRAY_PRE ? 0.0f : w[1];
        const float w2 = GRAY_PRE ? 0.0f : w[2];

        unsigned* cbA = cbw + (2 * g) * 528;
        unsigned* cbB = cbA + 528;

        // loader: win[j] = gray pixel j of the 40-px union window (adj) or
        // element j of rowA (j<32 -> re) handled by caller composition below.
        // Two passes, each reloads (compiler keeps addresses, re-reads data).

        // ---------- pass 1: even bins ----------
        {
            float win[40];
            if (GRAY_PRE && adj) {
                const float4* g4 = reinterpret_cast<const float4*>(x + baseA);
#pragma unroll
                for (int q = 0; q < 10; ++q) {
                    const float4 v = g4[q];
                    win[4 * q + 0] = v.x; win[4 * q + 1] = v.y;
                    win[4 * q + 2] = v.z; win[4 * q + 3] = v.w;
                }
            } else if (GRAY_PRE) {
#pragma unroll
                for (int i = 0; i < 32; ++i) win[i] = x[baseA + i];        // re source
#pragma unroll
                for (int i = 0; i < 8; ++i) win[32 + i] = 0.0f;            // unused
            } else {
#pragma unroll
                for (int i = 0; i < 32; ++i)
                    win[i] = w0 * x[baseA + i] + w1 * x[HW + baseA + i] + w2 * x[2 * HW + baseA + i];
#pragma unroll
                for (int i = 0; i < 8; ++i) win[32 + i] = 0.0f;
            }
            float er[16], ei[16];
            if (GRAY_PRE && adj) {
#pragma unroll
                for (int i = 0; i < 16; ++i) {
                    er[i] = win[i] + win[i + 16];
                    ei[i] = win[i + 8] + win[i + 24];
                }
            } else if (GRAY_PRE) {
#pragma unroll
                for (int i = 0; i < 16; ++i) {
                    er[i] = win[i] + win[i + 16];
                    ei[i] = x[baseB + i] + x[baseB + i + 16];
                }
            } else {
#pragma unroll
                for (int i = 0; i < 16; ++i) {
                    er[i] = win[i] + win[i + 16];
                    const float blo = w0 * x[baseB + i] + w1 * x[HW + baseB + i] + w2 * x[2 * HW + baseB + i];
                    const float bhi = w0 * x[baseB + i + 16] + w1 * x[HW + baseB + i + 16] + w2 * x[2 * HW + baseB + i + 16];
                    ei[i] = blo + bhi;
                }
            }
            fft16(er, ei);
            // X[0]=E[0], X[16]=E[8]; even slots k=2k2 use E[k2], E[16-k2]
            cbA[r] = pack_bf2(er[0], er[8]);
            cbB[r] = pack_bf2(ei[0], ei[8]);
#pragma unroll
            for (int k2 = 1; k2 <= 7; ++k2) {
                const int e1 = k2, e2 = 16 - k2;
                const float far_ = 0.5f * (er[e1] + er[e2]);
                const float fai_ = 0.5f * (ei[e1] - ei[e2]);
                const float fbr_ = 0.5f * (ei[e1] + ei[e2]);
                const float fbi_ = 0.5f * (er[e2] - er[e1]);
                cbA[(2 * k2) * 33 + r] = pack_bf2(far_, fai_);
                cbB[(2 * k2) * 33 + r] = pack_bf2(fbr_, fbi_);
            }
        }

        asm volatile("" ::: "memory");   // force pass-2 reload; keep FFT16s apart

        // ---------- pass 2: odd bins ----------
        {
            float win[40];
            if (GRAY_PRE && adj) {
                const float4* g4 = reinterpret_cast<const float4*>(x + baseA);
#pragma unroll
                for (int q = 0; q < 10; ++q) {
                    const float4 v = g4[q];
                    win[4 * q + 0] = v.x; win[4 * q + 1] = v.y;
                    win[4 * q + 2] = v.z; win[4 * q + 3] = v.w;
                }
            } else if (GRAY_PRE) {
#pragma unroll
                for (int i = 0; i < 32; ++i) win[i] = x[baseA + i];
#pragma unroll
                for (int i = 0; i < 8; ++i) win[32 + i] = 0.0f;
            } else {
#pragma unroll
                for (int i = 0; i < 32; ++i)
                    win[i] = w0 * x[baseA + i] + w1 * x[HW + baseA + i] + w2 * x[2 * HW + baseA + i];
#pragma unroll
                for (int i = 0; i < 8; ++i) win[32 + i] = 0.0f;
            }
            float orr[16], oi[16];
#pragma unroll
            for (int i = 0; i < 16; ++i) {
                float dre, dim;
                if (GRAY_PRE && adj) {
                    dre = win[i] - win[i + 16];
                    dim = win[i + 8] - win[i + 24];
                } else if (GRAY_PRE) {
                    dre = win[i] - win[i + 16];
                    dim = x[baseB + i] - x[baseB + i + 16];
                } else {
                    dre = win[i] - win[i + 16];
                    const float blo = w0 * x[baseB + i] + w1 * x[HW + baseB + i] + w2 * x[2 * HW + baseB + i];
                    const float bhi = w0 * x[baseB + i + 16] + w1 * x[HW + baseB + i + 16] + w2 * x[2 * HW + baseB + i + 16];
                    dim = blo - bhi;
                }
                orr[i] = dre * C32[i] + dim * S32[i];
                oi[i]  = dim * C32[i] - dre * S32[i];
            }
            fft16(orr, oi);
            // odd slots k=2k2+1 use O[k2], O[15-k2]
#pragma unroll
            for (int k2 = 0; k2 <= 7; ++k2) {
                const int o1 = k2, o2 = 15 - k2;
                const float far_ = 0.5f * (orr[o1] + orr[o2]);
                const float fai_ = 0.5f * (oi[o1] - oi[o2]);
                const float fbr_ = 0.5f * (oi[o1] + oi[o2]);
                const float fbi_ = 0.5f * (orr[o2] - orr[o1]);
                cbA[(2 * k2 + 1) * 33 + r] = pack_bf2(far_, fai_);
                cbB[(2 * k2 + 1) * 33 + r] = pack_bf2(fbr_, fbi_);
            }
        }
    }

    // waves don't share LDS: wave-local fence orders this wave's ds_writes
    // before its ds_reads (no s_barrier -> waves stay decoupled)
    asm volatile("s_waitcnt lgkmcnt(0)" ::: "memory");

    // ================= column stage =================
    {
        const int pl = lane >> 4, slot = lane & 15;
        const int p = P0 + pl;
        const unsigned* cbp = cbw + pl * 528 + slot * 33;
        const float b1f = (slot >= 7) ? 1.0f : 0.0f;
        const float m1f = (slot >= 8) ? 1.0f : 0.0f;

        float s0 = 0.0f, s1 = 0.0f;

        // ---------- pass 1: even kr ----------
        {
            float er[16], ei[16];
#pragma unroll
            for (int i = 0; i < 16; ++i) {
                const unsigned u0 = cbp[i], u1 = cbp[i + 16];
                er[i] = bf_hi(u0) + bf_hi(u1);
                ei[i] = bf_lo(u0) + bf_lo(u1);
            }
            fft16(er, ei);
            if (slot == 0) {
#pragma unroll
                for (int k2 = 0; k2 <= 8; ++k2) {
                    const int kr = 2 * k2;
                    const int a = k2, b = (k2 == 0) ? 0 : 16 - k2;
                    const float g0r = 0.5f * (er[a] + er[b]);
                    const float g0i = 0.5f * (ei[a] - ei[b]);
                    const float g1r = 0.5f * (ei[a] + ei[b]);
                    const float g1i = 0.5f * (er[b] - er[a]);
                    const float w0c = (kr >= 7 ? 1.0f : 0.0f) + ((kr >= 8 && kr <= 15) ? 1.0f : 0.0f);
                    const float w16c = 1.0f + ((kr >= 1 && kr <= 15) ? 1.0f : 0.0f);
                    if (w0c > 0.0f)
                        s0 = fmaf(w0c, __logf(g0r * g0r + g0i * g0i + 1.0f), s0);
                    s1 = fmaf(w16c, __logf(g1r * g1r + g1i * g1i + 1.0f), s1);
                }
            } else {
#pragma unroll
                for (int k2 = 0; k2 < 16; ++k2) {
                    const int kr = 2 * k2;
                    const float lp = __logf(er[k2] * er[k2] + ei[k2] * ei[k2] + 1.0f);
                    const float wgt = (kr >= 8 && kr <= 24) ? 2.0f : (b1f + m1f);
                    if (k2 & 1) s1 = fmaf(wgt, lp, s1);
                    else        s0 = fmaf(wgt, lp, s0);
                }
            }
        }

        asm volatile("" ::: "memory");   // force pass-2 LDS re-read

        // ---------- pass 2: odd kr ----------
        {
            float orr[16], oi[16];
#pragma unroll
            for (int i = 0; i < 16; ++i) {
                const unsigned u0 = cbp[i], u1 = cbp[i + 16];
                const float dre = bf_hi(u0) - bf_hi(u1);
                const float dim = bf_lo(u0) - bf_lo(u1);
                orr[i] = dre * C32[i] + dim * S32[i];
                oi[i]  = dim * C32[i] - dre * S32[i];
            }
            fft16(orr, oi);
            if (slot == 0) {
#pragma unroll
                for (int k2 = 0; k2 <= 7; ++k2) {
                    const int kr = 2 * k2 + 1;
                    const int a = k2, b = 15 - k2;
                    const float g0r = 0.5f * (orr[a] + orr[b]);
                    const float g0i = 0.5f * (oi[a] - oi[b]);
                    const float g1r = 0.5f * (oi[a] + oi[b]);
                    const float g1i = 0.5f * (orr[b] - orr[a]);
                    const float w0c = (kr >= 7 ? 1.0f : 0.0f) + ((kr >= 8 && kr <= 15) ? 1.0f : 0.0f);
                    const float w16c = 2.0f;   // kr in [1,15] always
                    if (w0c > 0.0f)
                        s0 = fmaf(w0c, __logf(g0r * g0r + g0i * g0i + 1.0f), s0);
                    s1 = fmaf(w16c, __logf(g1r * g1r + g1i * g1i + 1.0f), s1);
                }
            } else {
#pragma unroll
                for (int k2 = 0; k2 < 16; ++k2) {
                    const int kr = 2 * k2 + 1;
                    const float lp = __logf(orr[k2] * orr[k2] + oi[k2] * oi[k2] + 1.0f);
                    float wgt;
                    if (kr == 7)                   wgt = 1.0f + m1f;
                    else if (kr == 25)             wgt = b1f + 1.0f;
                    else if (kr >= 9 && kr <= 23)  wgt = 2.0f;
                    else                           wgt = b1f + m1f;
                    if (k2 & 1) s1 = fmaf(wgt, lp, s1);
                    else        s0 = fmaf(wgt, lp, s0);
                }
            }
        }

        float s = s0 + s1;
#pragma unroll
        for (int off = 8; off >= 1; off >>= 1) s += __shfl_xor(s, off, 16);
        if (slot == 0 && p < total) out[p] = s;
    }
}

// 8 blocks x 1024 threads; block b writes its partial max to partial[b]
__global__ __launch_bounds__(1024) void max_kernel(
        const float* __restrict__ sums, int n, float* __restrict__ partial) {
    __shared__ float sm[16];
    float m = 0.0f;  // sums are >= 0
    for (int i = blockIdx.x * 1024 + threadIdx.x; i < n; i += gridDim.x * 1024)
        m = fmaxf(m, sums[i]);
#pragma unroll
    for (int off = 32; off >= 1; off >>= 1) m = fmaxf(m, __shfl_xor(m, off, 64));
    if ((threadIdx.x & 63) == 0) sm[threadIdx.x >> 6] = m;
    __syncthreads();
    if (threadIdx.x == 0) {
#pragma unroll
        for (int i = 1; i < 16; ++i) m = fmaxf(m, sm[i]);
        partial[blockIdx.x] = m;
    }
}

__global__ __launch_bounds__(256) void norm_kernel(
        float* __restrict__ out, int n, const float* __restrict__ partial) {
    const int i = blockIdx.x * 256 + threadIdx.x;
    float m = partial[0];
#pragma unroll
    for (int b = 1; b < 8; ++b) m = fmaxf(m, partial[b]);
    if (i < n) out[i] = out[i] / m;
}

extern "C" void kernel_launch(void* const* d_in, const int* in_sizes, int n_in,
                              void* d_out, int out_size, void* d_ws, size_t ws_size,
                              hipStream_t stream) {
    const float* x = (const float*)d_in[0];
    const float* w = (const float*)d_in[1];
    float* out = (float*)d_out;

    const int HWi = in_sizes[0] / 3;
    const int H = (int)(sqrt((double)HWi) + 0.5);
    const int W = H;
    const long long HW = (long long)H * W;
    const int mat = (int)(sqrt((double)out_size) + 0.5);
    const int total = mat * mat;
    const int blocksA = (total + 7) / 8;

    float* partial = (float*)d_ws;                  // 8 floats
    float* gray = (float*)((char*)d_ws + 256);
    const size_t need = 256 + (size_t)HW * 4;

    if (ws_size >= need && (W & 3) == 0) {
        const int n4 = (int)(HW / 4);
        hipLaunchKernelGGL(gray_kernel, dim3((n4 + 255) / 256), dim3(256), 0, stream,
                           x, w, gray, n4, HW);
        hipLaunchKernelGGL((hfdft_patch_kernel<true>), dim3(blocksA), dim3(128), 0, stream,
                           gray, w, out, H, W, mat, mat);
    } else {
        hipLaunchKernelGGL((hfdft_patch_kernel<false>), dim3(blocksA), dim3(128), 0, stream,
                           x, w, out, H, W, mat, mat);
    }
    hipLaunchKernelGGL(max_kernel, dim3(8), dim3(1024), 0, stream, out, total, partial);
    hipLaunchKernelGGL(norm_kernel, dim3((total + 255) / 256), dim3(256), 0, stream,
                       out, total, partial);
}